// Round 1
// baseline (194.355 us; speedup 1.0000x reference)
//
#include <hip/hip_runtime.h>
#include <cstddef>

#define EPS 1e-9f
#define REG_MAX 16
#define TOPK 13
#define MAXL 8400

__device__ __forceinline__ float sigmoidf(float x){ return 1.0f/(1.0f+expf(-x)); }
__device__ __forceinline__ float bcef(float l, float t){
    return fmaxf(l,0.0f) - l*t + log1pf(expf(-fabsf(l)));
}
__device__ __forceinline__ float pow6f(float x){ float x2=x*x; return x2*x2*x2; }

// K1: DFL softmax decode -> pred_bboxes in anchor_s units; sigmoid(pred_scores)
__global__ void k_decode(const float* __restrict__ pred_scores,
                         const float* __restrict__ pred_distri,
                         const float* __restrict__ anchor_points,
                         const float* __restrict__ stride_t,
                         float* __restrict__ pred_bboxes,
                         float* __restrict__ sig,
                         int B, int L)
{
    int idx = blockIdx.x*blockDim.x + threadIdx.x;
    if (idx >= B*L) return;
    int l = idx % L;
    float v[68];
    const float4* pd4 = (const float4*)(pred_distri + (size_t)idx*68);
    #pragma unroll
    for (int i=0;i<17;i++){ float4 q = pd4[i]; v[4*i]=q.x; v[4*i+1]=q.y; v[4*i+2]=q.z; v[4*i+3]=q.w; }
    float dist[4];
    #pragma unroll
    for (int s=0;s<4;s++){
        float m = -1e30f;
        #pragma unroll
        for (int i=0;i<=REG_MAX;i++) m = fmaxf(m, v[s*17+i]);
        float sum=0.f, ws=0.f;
        #pragma unroll
        for (int i=0;i<=REG_MAX;i++){ float e = expf(v[s*17+i]-m); sum+=e; ws += e*(float)i; }
        dist[s] = ws/sum;
    }
    float st = stride_t[l];
    float ax = anchor_points[2*l]/st, ay = anchor_points[2*l+1]/st;
    float4 box = make_float4(ax-dist[0], ay-dist[1], ax+dist[2], ay+dist[3]);
    ((float4*)pred_bboxes)[idx] = box;
    sig[idx] = sigmoidf(pred_scores[idx]);
}

// K2: one block per (b,n): pairwise IoU row, metric = sig*iou^6*in_gt,
// iterative top-13 (lowest-index tie-break == jax.lax.top_k), write mask bytes.
__global__ void k_assign_topk(const float* __restrict__ pred_bboxes,
                              const float* __restrict__ sig,
                              const float* __restrict__ anchor_points,
                              const float* __restrict__ stride_t,
                              const float* __restrict__ gt_bboxes,
                              const float* __restrict__ pad_mask,
                              float* __restrict__ ious,
                              unsigned char* __restrict__ maskA,
                              int B,int N,int L)
{
    __shared__ float smet[MAXL];
    __shared__ float rv[256];
    __shared__ int   ri[256];
    __shared__ int   topk[TOPK];
    int bn = blockIdx.x; int b = bn / N; int n = bn % N; (void)n;
    const float4 gb = ((const float4*)gt_bboxes)[bn];
    float gx1=gb.x, gy1=gb.y, gx2=gb.z, gy2=gb.w;
    float ag = (gx2-gx1)*(gy2-gy1);
    int tid = threadIdx.x;
    for (int l=tid; l<L; l+=256){
        float4 pb = ((const float4*)pred_bboxes)[b*L + l];
        float st = stride_t[l];
        float p0 = pb.x*st, p1 = pb.y*st, p2 = pb.z*st, p3 = pb.w*st;
        float iw = fmaxf(fminf(gx2,p2)-fmaxf(gx1,p0), 0.f);
        float ih = fmaxf(fminf(gy2,p3)-fmaxf(gy1,p1), 0.f);
        float inter = iw*ih;
        float ap = (p2-p0)*(p3-p1);
        float iou = inter/(ag+ap-inter+EPS);
        ious[(size_t)bn*L + l] = iou;
        float apx = anchor_points[2*l], apy = anchor_points[2*l+1];
        bool ing = (apx-gx1>EPS)&&(apy-gy1>EPS)&&(gx2-apx>EPS)&&(gy2-apy>EPS);
        float metric = sig[b*L+l]*pow6f(iou);
        smet[l] = ing ? metric : 0.0f;
    }
    __syncthreads();
    for (int r=0;r<TOPK;r++){
        float bv=-1.f; int bl=0x7fffffff;
        for (int l=tid;l<L;l+=256){ float vv=smet[l]; if (vv>bv){bv=vv;bl=l;} }
        rv[tid]=bv; ri[tid]=bl; __syncthreads();
        for (int s=128;s>0;s>>=1){
            if (tid<s){
                if (rv[tid+s]>rv[tid] || (rv[tid+s]==rv[tid] && ri[tid+s]<ri[tid])){
                    rv[tid]=rv[tid+s]; ri[tid]=ri[tid+s];
                }
            }
            __syncthreads();
        }
        if (tid==0){ topk[r]=ri[0]; smet[ri[0]] = -1.0f; }
        __syncthreads();
    }
    if (pad_mask[bn] > 0.f && tid < TOPK){
        int l = topk[tid];
        float apx = anchor_points[2*l], apy = anchor_points[2*l+1];
        bool ing = (apx-gx1>EPS)&&(apy-gy1>EPS)&&(gx2-apx>EPS)&&(gy2-apy>EPS);
        if (ing) maskA[(size_t)(b*L+l)*N + n] = 1;
    }
}

// K3: per anchor: count assigned GTs; if >1 replace column with onehot(argmax_n iou)
__global__ void k_resolve(const unsigned char* __restrict__ maskA,
                          const float* __restrict__ ious,
                          unsigned int* __restrict__ words,
                          int B,int N,int L)
{
    int idx = blockIdx.x*blockDim.x + threadIdx.x;
    if (idx >= B*L) return;
    int b = idx / L, l = idx % L;
    const unsigned char* row = maskA + (size_t)idx*N;
    unsigned int w=0; int cnt=0;
    for (int n=0;n<N;n++){ if (row[n]){ w |= 1u<<n; cnt++; } }
    if (cnt > 1){
        float bv=-1e30f; int bbest=0;
        for (int n=0;n<N;n++){
            float vv = ious[((size_t)(b*N+n))*L + l];
            if (vv > bv){ bv=vv; bbest=n; }
        }
        w = 1u<<bbest;
    }
    words[idx] = w;
}

// K4: per (b,n): rowmax of metric*mask and iou*mask over L
__global__ void k_rowmax(const unsigned int* __restrict__ words,
                         const float* __restrict__ ious,
                         const float* __restrict__ sig,
                         float* __restrict__ rowmax_m,
                         float* __restrict__ rowmax_iou,
                         int B,int N,int L)
{
    __shared__ float rm[256], rio[256];
    int bn = blockIdx.x; int b = bn/N; int n = bn%N;
    int tid=threadIdx.x;
    float mm=0.f, mi=0.f;
    for (int l=tid;l<L;l+=256){
        unsigned int w = words[b*L+l];
        if ((w>>n)&1u){
            float iou = ious[(size_t)bn*L+l];
            float met = sig[b*L+l]*pow6f(iou);
            mm = fmaxf(mm, met); mi = fmaxf(mi, iou);
        }
    }
    rm[tid]=mm; rio[tid]=mi; __syncthreads();
    for (int s=128;s>0;s>>=1){
        if (tid<s){ rm[tid]=fmaxf(rm[tid],rm[tid+s]); rio[tid]=fmaxf(rio[tid],rio[tid+s]); }
        __syncthreads();
    }
    if (tid==0){ rowmax_m[bn]=rm[0]; rowmax_iou[bn]=rio[0]; }
}

// K5: per-anchor loss terms, block-reduced into 8 partial sums per block
__global__ void k_loss(const float* __restrict__ pred_scores,
                       const float* __restrict__ pred_distri,
                       const float* __restrict__ pose_logits,
                       const float* __restrict__ anchor_points,
                       const float* __restrict__ stride_t,
                       const float* __restrict__ gt_bboxes,
                       const float* __restrict__ gt_poses,
                       const float* __restrict__ sigmas,
                       const int*   __restrict__ gt_class,
                       const float* __restrict__ pred_bboxes,
                       const float* __restrict__ sig,
                       const float* __restrict__ ious,
                       const unsigned int* __restrict__ words,
                       const float* __restrict__ rowmax_m,
                       const float* __restrict__ rowmax_iou,
                       float* __restrict__ partials,
                       int B,int N,int L,int J)
{
    int idx = blockIdx.x*blockDim.x + threadIdx.x;
    float a_score=0, a_cls=0, a_giou=0, a_dfl=0, a_pos=0, a_kmf=0, a_preg=0, a_pcls=0;
    if (idx < B*L){
        int b=idx/L, l=idx%L;
        unsigned int w = words[idx];
        bool pos = (w!=0u);
        int gi = pos ? (__ffs(w)-1) : 0;
        float score = 0.f;
        unsigned int ww=w;
        while (ww){
            int n = __ffs(ww)-1; ww &= ww-1u;
            float iou = ious[((size_t)(b*N+n))*L + l];
            float met = sig[idx]*pow6f(iou);
            float vv = met/(rowmax_m[b*N+n]+EPS)*rowmax_iou[b*N+n];
            score = fmaxf(score, vv);
        }
        int acls = pos ? gt_class[b*N+gi] : 1; // NUM_CLASSES=1 sentinel when neg
        float assigned = (pos && acls==0) ? score : 0.f;
        float logit = pred_scores[idx];
        float sg = sig[idx];
        float wg = sg - assigned; wg *= wg;
        a_cls = wg * bcef(logit, assigned);
        a_score = assigned;
        if (pos){
            a_pos = 1.f;
            float st = stride_t[l];
            const float4 gb4 = ((const float4*)gt_bboxes)[b*N+gi];
            float ab0=gb4.x/st, ab1=gb4.y/st, ab2=gb4.z/st, ab3=gb4.w/st;
            float area = (ab2-ab0)*(ab3-ab1);
            float apx = anchor_points[2*l]/st, apy = anchor_points[2*l+1]/st;
            float bw = assigned; // bbox_w = assigned_scores.sum(-1)*posf
            if (bw > 0.f){
                float4 pb = ((const float4*)pred_bboxes)[idx];
                float iw = fmaxf(fminf(pb.z,ab2)-fmaxf(pb.x,ab0),0.f);
                float ih = fmaxf(fminf(pb.w,ab3)-fmaxf(pb.y,ab1),0.f);
                float inter=iw*ih;
                float a1=(pb.z-pb.x)*(pb.w-pb.y);
                float a2=(ab2-ab0)*(ab3-ab1);
                float uni=a1+a2-inter+EPS;
                float iou=inter/uni;
                float cw=fmaxf(pb.z,ab2)-fminf(pb.x,ab0);
                float ch=fmaxf(pb.w,ab3)-fminf(pb.y,ab1);
                float ac=cw*ch+EPS;
                float g = 1.f-(iou-(ac-uni)/ac);
                a_giou = g*bw;
                // DFL
                float t4[4] = { apx-ab0, apy-ab1, ab2-apx, ab3-apy };
                const float* pdist = pred_distri + (size_t)idx*68;
                float dfl=0.f;
                #pragma unroll
                for (int s2=0;s2<4;s2++){
                    float tt = fminf(fmaxf(t4[s2],0.f),(float)REG_MAX-0.01f);
                    int tl = (int)floorf(tt);
                    float wl = (float)tl + 1.f - tt;
                    float m=-1e30f;
                    for (int i=0;i<=REG_MAX;i++) m=fmaxf(m,pdist[s2*17+i]);
                    float se=0.f;
                    for (int i=0;i<=REG_MAX;i++) se+=expf(pdist[s2*17+i]-m);
                    float lse = m + logf(se);
                    float ll = -(pdist[s2*17+tl]-lse);
                    float lr = -(pdist[s2*17+tl+1]-lse);
                    dfl += ll*wl + lr*(1.f-wl);
                }
                a_dfl = dfl*0.25f*bw;
            }
            // pose (only pos anchors contribute: every term gated by posf/kmf)
            const float* gp = gt_poses + ((size_t)(b*N+gi))*J*3;
            const float* pl = pose_logits + (size_t)idx*J*3;
            for (int j=0;j<J;j++){
                float gx=gp[3*j]/st, gy=gp[3*j+1]/st, vis=gp[3*j+2];
                float px=pl[3*j]+apx, py=pl[3*j+1]+apy, pz=pl[3*j+2];
                float kmf = (vis!=0.f)?1.f:0.f;
                float dx=px-gx, dy=py-gy;
                float d = dx*dx+dy*dy;
                float s2g = 2.f*sigmas[j]; s2g*=s2g;
                float e = d/s2g/(area+EPS)/2.f;
                a_preg += (1.f-expf(-e))*kmf;
                a_kmf  += kmf;
                a_pcls += bcef(pz, kmf);
            }
        }
    }
    __shared__ float red[256];
    float acc[8] = {a_score,a_cls,a_giou,a_dfl,a_pos,a_kmf,a_preg,a_pcls};
    #pragma unroll
    for (int k=0;k<8;k++){
        red[threadIdx.x]=acc[k]; __syncthreads();
        for (int s=128;s>0;s>>=1){
            if (threadIdx.x<s) red[threadIdx.x]+=red[threadIdx.x+s];
            __syncthreads();
        }
        if (threadIdx.x==0) partials[(size_t)blockIdx.x*8+k]=red[0];
        __syncthreads();
    }
}

// K6: deterministic final reduction + loss assembly -> 7 floats
__global__ void k_final(const float* __restrict__ partials, int nblk, int J,
                        float* __restrict__ out)
{
    __shared__ float s[8];
    int tid=threadIdx.x;
    if (tid<8){
        float acc=0.f;
        for (int i=0;i<nblk;i++) acc += partials[(size_t)i*8+tid];
        s[tid]=acc;
    }
    __syncthreads();
    if (tid==0){
        float ass  = fmaxf(s[0],1.f);
        float lcls = s[1]/ass;
        float liou = s[2]/ass;
        float ldfl = s[3]/ass;
        float npk  = fmaxf(s[4]*(float)J,1.f);
        float factor = npk/(s[5]+EPS);
        float preg = factor*s[6]/npk;
        float pcls = s[7]/npk;
        float loss = lcls + 2.5f*liou + 0.5f*ldfl + pcls + preg;
        out[0]=loss; out[1]=lcls; out[2]=liou; out[3]=ldfl;
        out[4]=pcls; out[5]=preg; out[6]=loss;
    }
}

extern "C" void kernel_launch(void* const* d_in, const int* in_sizes, int n_in,
                              void* d_out, int out_size, void* d_ws, size_t ws_size,
                              hipStream_t stream)
{
    const float* pred_scores   = (const float*)d_in[0];
    const float* pred_distri   = (const float*)d_in[1];
    const float* pose_logits   = (const float*)d_in[2];
    const float* anchor_points = (const float*)d_in[3];
    const float* stride_t      = (const float*)d_in[4];
    const float* gt_bboxes     = (const float*)d_in[5];
    const float* pad_mask      = (const float*)d_in[6];
    const float* gt_poses      = (const float*)d_in[7];
    const float* sigmas        = (const float*)d_in[8];
    const int*   gt_class      = (const int*)d_in[9];

    int L = in_sizes[3]/2;
    int B = in_sizes[0]/L;
    int N = in_sizes[5]/(B*4);
    int J = in_sizes[8];

    char* ws = (char*)d_ws;
    size_t off=0;
    auto alloc=[&](size_t bytes)->void*{
        size_t cur=off; off += (bytes+255)/256*256; return (void*)(ws+cur);
    };
    float* ious         = (float*)alloc((size_t)B*N*L*4);
    float* pred_bboxes  = (float*)alloc((size_t)B*L*4*4);
    float* sig          = (float*)alloc((size_t)B*L*4);
    unsigned char* maskA= (unsigned char*)alloc((size_t)B*L*N);
    unsigned int* words = (unsigned int*)alloc((size_t)B*L*4);
    float* rowmax_m     = (float*)alloc((size_t)B*N*4);
    float* rowmax_i     = (float*)alloc((size_t)B*N*4);
    int nblk = (B*L+255)/256;
    float* partials     = (float*)alloc((size_t)nblk*8*4);
    (void)ws_size; (void)n_in; (void)out_size;

    hipMemsetAsync(maskA, 0, (size_t)B*L*N, stream);
    k_decode<<<nblk,256,0,stream>>>(pred_scores,pred_distri,anchor_points,stride_t,
                                    pred_bboxes,sig,B,L);
    k_assign_topk<<<B*N,256,0,stream>>>(pred_bboxes,sig,anchor_points,stride_t,
                                        gt_bboxes,pad_mask,ious,maskA,B,N,L);
    k_resolve<<<nblk,256,0,stream>>>(maskA,ious,words,B,N,L);
    k_rowmax<<<B*N,256,0,stream>>>(words,ious,sig,rowmax_m,rowmax_i,B,N,L);
    k_loss<<<nblk,256,0,stream>>>(pred_scores,pred_distri,pose_logits,anchor_points,
                                  stride_t,gt_bboxes,gt_poses,sigmas,gt_class,
                                  pred_bboxes,sig,ious,words,rowmax_m,rowmax_i,
                                  partials,B,N,L,J);
    k_final<<<1,64,0,stream>>>(partials,nblk,J,(float*)d_out);
}

// Round 3
// 136.871 us; speedup vs baseline: 1.4200x; 1.4200x over previous
//
#include <hip/hip_runtime.h>
#include <cstddef>

#define EPS 1e-9f
#define REG_MAX 16
#define TOPK 13
#define MAXL 8400

__device__ __forceinline__ float sigmoidf(float x){ return 1.0f/(1.0f+expf(-x)); }
__device__ __forceinline__ float bcef(float l, float t){
    return fmaxf(l,0.0f) - l*t + log1pf(expf(-fabsf(l)));
}
__device__ __forceinline__ float pow6f(float x){ float x2=x*x; return x2*x2*x2; }

// K1: DFL softmax decode -> pred_bboxes in anchor_s units; sigmoid(pred_scores)
__global__ void k_decode(const float* __restrict__ pred_scores,
                         const float* __restrict__ pred_distri,
                         const float* __restrict__ anchor_points,
                         const float* __restrict__ stride_t,
                         float* __restrict__ pred_bboxes,
                         float* __restrict__ sig,
                         int B, int L)
{
    int idx = blockIdx.x*blockDim.x + threadIdx.x;
    if (idx >= B*L) return;
    int l = idx % L;
    float v[68];
    const float4* pd4 = (const float4*)(pred_distri + (size_t)idx*68);
    #pragma unroll
    for (int i=0;i<17;i++){ float4 q = pd4[i]; v[4*i]=q.x; v[4*i+1]=q.y; v[4*i+2]=q.z; v[4*i+3]=q.w; }
    float dist[4];
    #pragma unroll
    for (int s=0;s<4;s++){
        float m = -1e30f;
        #pragma unroll
        for (int i=0;i<=REG_MAX;i++) m = fmaxf(m, v[s*17+i]);
        float sum=0.f, ws=0.f;
        #pragma unroll
        for (int i=0;i<=REG_MAX;i++){ float e = expf(v[s*17+i]-m); sum+=e; ws += e*(float)i; }
        dist[s] = ws/sum;
    }
    float st = stride_t[l];
    float ax = anchor_points[2*l]/st, ay = anchor_points[2*l+1]/st;
    float4 box = make_float4(ax-dist[0], ay-dist[1], ax+dist[2], ay+dist[3]);
    ((float4*)pred_bboxes)[idx] = box;
    sig[idx] = sigmoidf(pred_scores[idx]);
}

// K2: one block per (b,n): pairwise IoU row, metric = sig*iou^6*in_gt,
// iterative top-13 (lowest-index tie-break == jax.lax.top_k).
// Round 2: wave-level __shfl_xor butterfly argmax (2 syncs/round, was 9).
__global__ void k_assign_topk(const float* __restrict__ pred_bboxes,
                              const float* __restrict__ sig,
                              const float* __restrict__ anchor_points,
                              const float* __restrict__ stride_t,
                              const float* __restrict__ gt_bboxes,
                              const float* __restrict__ pad_mask,
                              float* __restrict__ ious,
                              unsigned char* __restrict__ maskA,
                              int B,int N,int L)
{
    __shared__ float smet[MAXL];
    __shared__ float wv[4];
    __shared__ int   wi[4];
    __shared__ int   topk[TOPK];
    int bn = blockIdx.x; int b = bn / N; int n = bn % N;
    const float4 gb = ((const float4*)gt_bboxes)[bn];
    float gx1=gb.x, gy1=gb.y, gx2=gb.z, gy2=gb.w;
    float ag = (gx2-gx1)*(gy2-gy1);
    int tid = threadIdx.x;
    for (int l=tid; l<L; l+=256){
        float4 pb = ((const float4*)pred_bboxes)[b*L + l];
        float st = stride_t[l];
        float p0 = pb.x*st, p1 = pb.y*st, p2 = pb.z*st, p3 = pb.w*st;
        float iw = fmaxf(fminf(gx2,p2)-fmaxf(gx1,p0), 0.f);
        float ih = fmaxf(fminf(gy2,p3)-fmaxf(gy1,p1), 0.f);
        float inter = iw*ih;
        float ap = (p2-p0)*(p3-p1);
        float iou = inter/(ag+ap-inter+EPS);
        ious[(size_t)bn*L + l] = iou;
        float apx = anchor_points[2*l], apy = anchor_points[2*l+1];
        bool ing = (apx-gx1>EPS)&&(apy-gy1>EPS)&&(gx2-apx>EPS)&&(gy2-apy>EPS);
        float metric = sig[b*L+l]*pow6f(iou);
        smet[l] = ing ? metric : 0.0f;
    }
    __syncthreads();
    for (int r=0;r<TOPK;r++){
        float bv=-1.f; int bl=0x7fffffff;
        // strict > + ascending scan keeps lowest index per thread
        for (int l=tid;l<L;l+=256){ float vv=smet[l]; if (vv>bv){bv=vv;bl=l;} }
        // 64-lane butterfly; (>, or == with lower idx) is order-independent
        #pragma unroll
        for (int off=32; off>0; off>>=1){
            float ov = __shfl_xor(bv, off);
            int   oi = __shfl_xor(bl, off);
            if (ov>bv || (ov==bv && oi<bl)){ bv=ov; bl=oi; }
        }
        if ((tid&63)==0){ wv[tid>>6]=bv; wi[tid>>6]=bl; }
        __syncthreads();
        if (tid==0){
            float fv=wv[0]; int fi=wi[0];
            #pragma unroll
            for (int w2=1;w2<4;w2++){
                if (wv[w2]>fv || (wv[w2]==fv && wi[w2]<fi)){ fv=wv[w2]; fi=wi[w2]; }
            }
            topk[r]=fi; smet[fi] = -1.0f;
        }
        __syncthreads();
    }
    if (pad_mask[bn] > 0.f && tid < TOPK){
        int l = topk[tid];
        float apx = anchor_points[2*l], apy = anchor_points[2*l+1];
        bool ing = (apx-gx1>EPS)&&(apy-gy1>EPS)&&(gx2-apx>EPS)&&(gy2-apy>EPS);
        if (ing) maskA[(size_t)(b*L+l)*N + n] = 1;
    }
}

// K3: per anchor: count assigned GTs; if >1 replace column with onehot(argmax_n iou)
__global__ void k_resolve(const unsigned char* __restrict__ maskA,
                          const float* __restrict__ ious,
                          unsigned int* __restrict__ words,
                          int B,int N,int L)
{
    int idx = blockIdx.x*blockDim.x + threadIdx.x;
    if (idx >= B*L) return;
    int b = idx / L, l = idx % L;
    const unsigned char* row = maskA + (size_t)idx*N;
    unsigned int w=0; int cnt=0;
    for (int n=0;n<N;n++){ if (row[n]){ w |= 1u<<n; cnt++; } }
    if (cnt > 1){
        float bv=-1e30f; int bbest=0;
        for (int n=0;n<N;n++){
            float vv = ious[((size_t)(b*N+n))*L + l];
            if (vv > bv){ bv=vv; bbest=n; }
        }
        w = 1u<<bbest;
    }
    words[idx] = w;
}

// K4: per (b,n): rowmax of metric*mask and iou*mask over L
__global__ void k_rowmax(const unsigned int* __restrict__ words,
                         const float* __restrict__ ious,
                         const float* __restrict__ sig,
                         float* __restrict__ rowmax_m,
                         float* __restrict__ rowmax_iou,
                         int B,int N,int L)
{
    __shared__ float rm[256], rio[256];
    int bn = blockIdx.x; int b = bn/N; int n = bn%N;
    int tid=threadIdx.x;
    float mm=0.f, mi=0.f;
    for (int l=tid;l<L;l+=256){
        unsigned int w = words[b*L+l];
        if ((w>>n)&1u){
            float iou = ious[(size_t)bn*L+l];
            float met = sig[b*L+l]*pow6f(iou);
            mm = fmaxf(mm, met); mi = fmaxf(mi, iou);
        }
    }
    rm[tid]=mm; rio[tid]=mi; __syncthreads();
    for (int s=128;s>0;s>>=1){
        if (tid<s){ rm[tid]=fmaxf(rm[tid],rm[tid+s]); rio[tid]=fmaxf(rio[tid],rio[tid+s]); }
        __syncthreads();
    }
    if (tid==0){ rowmax_m[bn]=rm[0]; rowmax_iou[bn]=rio[0]; }
}

// K5: per-anchor loss terms, block-reduced into 8 partial sums per block
__global__ void k_loss(const float* __restrict__ pred_scores,
                       const float* __restrict__ pred_distri,
                       const float* __restrict__ pose_logits,
                       const float* __restrict__ anchor_points,
                       const float* __restrict__ stride_t,
                       const float* __restrict__ gt_bboxes,
                       const float* __restrict__ gt_poses,
                       const float* __restrict__ sigmas,
                       const int*   __restrict__ gt_class,
                       const float* __restrict__ pred_bboxes,
                       const float* __restrict__ sig,
                       const float* __restrict__ ious,
                       const unsigned int* __restrict__ words,
                       const float* __restrict__ rowmax_m,
                       const float* __restrict__ rowmax_iou,
                       float* __restrict__ partials,
                       int B,int N,int L,int J)
{
    int idx = blockIdx.x*blockDim.x + threadIdx.x;
    float a_score=0, a_cls=0, a_giou=0, a_dfl=0, a_pos=0, a_kmf=0, a_preg=0, a_pcls=0;
    if (idx < B*L){
        int b=idx/L, l=idx%L;
        unsigned int w = words[idx];
        bool pos = (w!=0u);
        int gi = pos ? (__ffs(w)-1) : 0;
        float score = 0.f;
        unsigned int ww=w;
        while (ww){
            int n = __ffs(ww)-1; ww &= ww-1u;
            float iou = ious[((size_t)(b*N+n))*L + l];
            float met = sig[idx]*pow6f(iou);
            float vv = met/(rowmax_m[b*N+n]+EPS)*rowmax_iou[b*N+n];
            score = fmaxf(score, vv);
        }
        int acls = pos ? gt_class[b*N+gi] : 1; // NUM_CLASSES=1 sentinel when neg
        float assigned = (pos && acls==0) ? score : 0.f;
        float logit = pred_scores[idx];
        float sg = sig[idx];
        float wg = sg - assigned; wg *= wg;
        a_cls = wg * bcef(logit, assigned);
        a_score = assigned;
        if (pos){
            a_pos = 1.f;
            float st = stride_t[l];
            const float4 gb4 = ((const float4*)gt_bboxes)[b*N+gi];
            float ab0=gb4.x/st, ab1=gb4.y/st, ab2=gb4.z/st, ab3=gb4.w/st;
            float area = (ab2-ab0)*(ab3-ab1);
            float apx = anchor_points[2*l]/st, apy = anchor_points[2*l+1]/st;
            float bw = assigned; // bbox_w = assigned_scores.sum(-1)*posf
            if (bw > 0.f){
                float4 pb = ((const float4*)pred_bboxes)[idx];
                float iw = fmaxf(fminf(pb.z,ab2)-fmaxf(pb.x,ab0),0.f);
                float ih = fmaxf(fminf(pb.w,ab3)-fmaxf(pb.y,ab1),0.f);
                float inter=iw*ih;
                float a1=(pb.z-pb.x)*(pb.w-pb.y);
                float a2=(ab2-ab0)*(ab3-ab1);
                float uni=a1+a2-inter+EPS;
                float iou=inter/uni;
                float cw=fmaxf(pb.z,ab2)-fminf(pb.x,ab0);
                float ch=fmaxf(pb.w,ab3)-fminf(pb.y,ab1);
                float ac=cw*ch+EPS;
                float g = 1.f-(iou-(ac-uni)/ac);
                a_giou = g*bw;
                // DFL
                float t4[4] = { apx-ab0, apy-ab1, ab2-apx, ab3-apy };
                const float* pdist = pred_distri + (size_t)idx*68;
                float dfl=0.f;
                #pragma unroll
                for (int s2=0;s2<4;s2++){
                    float tt = fminf(fmaxf(t4[s2],0.f),(float)REG_MAX-0.01f);
                    int tl = (int)floorf(tt);
                    float wl = (float)tl + 1.f - tt;
                    float m=-1e30f;
                    for (int i=0;i<=REG_MAX;i++) m=fmaxf(m,pdist[s2*17+i]);
                    float se=0.f;
                    for (int i=0;i<=REG_MAX;i++) se+=expf(pdist[s2*17+i]-m);
                    float lse = m + logf(se);
                    float ll = -(pdist[s2*17+tl]-lse);
                    float lr = -(pdist[s2*17+tl+1]-lse);
                    dfl += ll*wl + lr*(1.f-wl);
                }
                a_dfl = dfl*0.25f*bw;
            }
            // pose (only pos anchors contribute: every term gated by posf/kmf)
            const float* gp = gt_poses + ((size_t)(b*N+gi))*J*3;
            const float* pl = pose_logits + (size_t)idx*J*3;
            for (int j=0;j<J;j++){
                float gx=gp[3*j]/st, gy=gp[3*j+1]/st, vis=gp[3*j+2];
                float px=pl[3*j]+apx, py=pl[3*j+1]+apy, pz=pl[3*j+2];
                float kmf = (vis!=0.f)?1.f:0.f;
                float dx=px-gx, dy=py-gy;
                float d = dx*dx+dy*dy;
                float s2g = 2.f*sigmas[j]; s2g*=s2g;
                float e = d/s2g/(area+EPS)/2.f;
                a_preg += (1.f-expf(-e))*kmf;
                a_kmf  += kmf;
                a_pcls += bcef(pz, kmf);
            }
        }
    }
    __shared__ float red[256];
    float acc[8] = {a_score,a_cls,a_giou,a_dfl,a_pos,a_kmf,a_preg,a_pcls};
    #pragma unroll
    for (int k=0;k<8;k++){
        red[threadIdx.x]=acc[k]; __syncthreads();
        for (int s=128;s>0;s>>=1){
            if (threadIdx.x<s) red[threadIdx.x]+=red[threadIdx.x+s];
            __syncthreads();
        }
        if (threadIdx.x==0) partials[(size_t)blockIdx.x*8+k]=red[0];
        __syncthreads();
    }
}

// K6: deterministic parallel final reduction + loss assembly -> 7 floats
// (256 threads — launch config MUST be <<<1,256>>>, round-2 bug was <<<1,64>>>)
__global__ void k_final(const float* __restrict__ partials, int nblk, int J,
                        float* __restrict__ out)
{
    __shared__ float red[256][9]; // pad to 9 to avoid bank conflicts
    int tid = threadIdx.x;
    float acc[8] = {0,0,0,0,0,0,0,0};
    for (int i=tid; i<nblk; i+=256){
        const float4* p = (const float4*)(partials + (size_t)i*8);
        float4 a = p[0], b = p[1];
        acc[0]+=a.x; acc[1]+=a.y; acc[2]+=a.z; acc[3]+=a.w;
        acc[4]+=b.x; acc[5]+=b.y; acc[6]+=b.z; acc[7]+=b.w;
    }
    #pragma unroll
    for (int k=0;k<8;k++) red[tid][k]=acc[k];
    __syncthreads();
    for (int s=128;s>0;s>>=1){
        if (tid<s){
            #pragma unroll
            for (int k=0;k<8;k++) red[tid][k]+=red[tid+s][k];
        }
        __syncthreads();
    }
    if (tid==0){
        float ass  = fmaxf(red[0][0],1.f);
        float lcls = red[0][1]/ass;
        float liou = red[0][2]/ass;
        float ldfl = red[0][3]/ass;
        float npk  = fmaxf(red[0][4]*(float)J,1.f);
        float factor = npk/(red[0][5]+EPS);
        float preg = factor*red[0][6]/npk;
        float pcls = red[0][7]/npk;
        float loss = lcls + 2.5f*liou + 0.5f*ldfl + pcls + preg;
        out[0]=loss; out[1]=lcls; out[2]=liou; out[3]=ldfl;
        out[4]=pcls; out[5]=preg; out[6]=loss;
    }
}

extern "C" void kernel_launch(void* const* d_in, const int* in_sizes, int n_in,
                              void* d_out, int out_size, void* d_ws, size_t ws_size,
                              hipStream_t stream)
{
    const float* pred_scores   = (const float*)d_in[0];
    const float* pred_distri   = (const float*)d_in[1];
    const float* pose_logits   = (const float*)d_in[2];
    const float* anchor_points = (const float*)d_in[3];
    const float* stride_t      = (const float*)d_in[4];
    const float* gt_bboxes     = (const float*)d_in[5];
    const float* pad_mask      = (const float*)d_in[6];
    const float* gt_poses      = (const float*)d_in[7];
    const float* sigmas        = (const float*)d_in[8];
    const int*   gt_class      = (const int*)d_in[9];

    int L = in_sizes[3]/2;
    int B = in_sizes[0]/L;
    int N = in_sizes[5]/(B*4);
    int J = in_sizes[8];

    char* ws = (char*)d_ws;
    size_t off=0;
    auto alloc=[&](size_t bytes)->void*{
        size_t cur=off; off += (bytes+255)/256*256; return (void*)(ws+cur);
    };
    float* ious         = (float*)alloc((size_t)B*N*L*4);
    float* pred_bboxes  = (float*)alloc((size_t)B*L*4*4);
    float* sig          = (float*)alloc((size_t)B*L*4);
    unsigned char* maskA= (unsigned char*)alloc((size_t)B*L*N);
    unsigned int* words = (unsigned int*)alloc((size_t)B*L*4);
    float* rowmax_m     = (float*)alloc((size_t)B*N*4);
    float* rowmax_i     = (float*)alloc((size_t)B*N*4);
    int nblk = (B*L+255)/256;
    float* partials     = (float*)alloc((size_t)nblk*8*4);
    (void)ws_size; (void)n_in; (void)out_size;

    hipMemsetAsync(maskA, 0, (size_t)B*L*N, stream);
    k_decode<<<nblk,256,0,stream>>>(pred_scores,pred_distri,anchor_points,stride_t,
                                    pred_bboxes,sig,B,L);
    k_assign_topk<<<B*N,256,0,stream>>>(pred_bboxes,sig,anchor_points,stride_t,
                                        gt_bboxes,pad_mask,ious,maskA,B,N,L);
    k_resolve<<<nblk,256,0,stream>>>(maskA,ious,words,B,N,L);
    k_rowmax<<<B*N,256,0,stream>>>(words,ious,sig,rowmax_m,rowmax_i,B,N,L);
    k_loss<<<nblk,256,0,stream>>>(pred_scores,pred_distri,pose_logits,anchor_points,
                                  stride_t,gt_bboxes,gt_poses,sigmas,gt_class,
                                  pred_bboxes,sig,ious,words,rowmax_m,rowmax_i,
                                  partials,B,N,L,J);
    k_final<<<1,256,0,stream>>>(partials,nblk,J,(float*)d_out);
}